// Round 1
// baseline (636.283 us; speedup 1.0000x reference)
//
#include <hip/hip_runtime.h>
#include <math.h>

#define BLOCK 512
#define JMAX 13

// ---------------------------------------------------------------------------
// Kernel 1: filters output (64 x 201), written to the tail of d_out.
// Mirrors _get_filters exactly in fp32.
// ---------------------------------------------------------------------------
__global__ void fse_filters(const float* __restrict__ low_hz_,
                            const float* __restrict__ band_hz_,
                            float* __restrict__ out)
{
    int idx = blockIdx.x * 256 + threadIdx.x;
    if (idx >= 64 * 201) return;
    int c = idx / 201;
    int k = idx - c * 201;
    float lo = 50.0f + fabsf(low_hz_[c]);
    float hi = lo + 50.0f + fabsf(band_hz_[c]);
    hi = fminf(fmaxf(hi, 50.0f), 8000.0f);
    float ctr = 0.5f * (lo + hi);
    float hbw = 0.5f * (hi - lo);
    float fq = 40.0f * (float)k;
    float resp = 1.0f - fabsf(fq - ctr) / hbw;
    out[idx] = (fq >= lo && fq <= hi) ? resp : 0.0f;
}

// ---------------------------------------------------------------------------
// Kernel 2: fully fused main pipeline. One block per batch item.
//  - stage reflect-padded waveform (16400 f32) in LDS
//  - per wave: 13 frames share one rotation recurrence per bin (4 bin-groups)
//  - Hann applied in freq domain: Xw[k] = 0.5 X[k] - 0.25 (X[k-1]+X[k+1])
//  - analytic triangular filters (only ~2-10 bins per channel)
//  - block-wide LayerNorm (two-pass), log10(x^2+1e-6), linear interp 101->64
// ---------------------------------------------------------------------------
__global__ __launch_bounds__(512, 2)
void fse_main(const float* __restrict__ wav,
              const float* __restrict__ low_hz_,
              const float* __restrict__ band_hz_,
              const float* __restrict__ ln_w,
              const float* __restrict__ ln_b,
              float* __restrict__ out)
{
    __shared__ float  xp[16400];        // reflect-padded waveform
    __shared__ float2 Xs[8][204];       // per-wave complex spectrum scratch
    __shared__ float  mags[8][204];     // per-wave magnitude scratch
    __shared__ float  fbuf[64 * 101];   // filtered[c][t]
    __shared__ float  fctr[64], finv[64];
    __shared__ int    fks[64], fke[64];
    __shared__ float  red[8];
    __shared__ float  stats[2];

    const int b    = blockIdx.x;
    const int tid  = threadIdx.x;
    const int w    = tid >> 6;      // wave id 0..7
    const int lane = tid & 63;
    const float* __restrict__ x = wav + b * 16000;

    // ---- stage waveform with reflect padding (pad=200 each side) ----
    for (int i = tid; i < 16400; i += BLOCK) {
        int p = i - 200;
        p = (p < 0) ? -p : p;
        p = (p > 15999) ? (31998 - p) : p;
        xp[i] = x[p];
    }

    // ---- per-channel filter params (thread c = tid < 64) ----
    if (tid < 64) {
        float lo = 50.0f + fabsf(low_hz_[tid]);
        float hi = lo + 50.0f + fabsf(band_hz_[tid]);
        hi = fminf(fmaxf(hi, 50.0f), 8000.0f);
        float ctr = 0.5f * (lo + hi);
        float hbw = 0.5f * (hi - lo);
        int ks = (int)ceilf(lo * 0.025f);
        if (ks < 0) ks = 0;
        while (40.0f * (float)ks < lo) ++ks;                     // match freq >= low
        while (ks > 0 && 40.0f * (float)(ks - 1) >= lo) --ks;
        int ke = (int)floorf(hi * 0.025f);
        if (ke > 200) ke = 200;
        while (40.0f * (float)ke > hi) --ke;                     // match freq <= high
        while (ke < 200 && 40.0f * (float)(ke + 1) <= hi) ++ke;
        fctr[tid] = ctr;
        finv[tid] = (hbw > 0.0f) ? (1.0f / hbw) : 0.0f;
        fks[tid]  = ks;
        fke[tid]  = ke;
    }
    __syncthreads();

    const float cctr = fctr[lane];
    const float cinv = finv[lane];
    const int   cks  = fks[lane];
    const int   cke  = fke[lane];

    // ---- DFT: wave w handles frames t = w + 8j (j = 0..12, clamped) ----
    // bins k = 64*m + lane for m = 0..3 (k <= 201 used)
    float reX[4][JMAX], imX[4][JMAX];
    const float2* __restrict__ xp2 = (const float2*)xp;

    #pragma unroll
    for (int m = 0; m < 4; ++m) {
        const int k = m * 64 + lane;
        const float th = -0.015707963267948966f * (float)k;   // -2*pi*k/400
        float s1, c1, sd, cd;
        sincosf(th, &s1, &c1);            // phase at n=1
        sincosf(th + th, &sd, &cd);       // step (2 samples per iter)
        float c0 = 1.0f, s0 = 0.0f;       // phase at n=0
        #pragma unroll
        for (int j = 0; j < JMAX; ++j) { reX[m][j] = 0.0f; imX[m][j] = 0.0f; }

        int ib = 80 * w;                  // float2 index of xp[160*w + n]/2
        #pragma unroll 2
        for (int h = 0; h < 200; ++h) {
            float2 f[JMAX];
            #pragma unroll
            for (int j = 0; j < JMAX; ++j) f[j] = xp2[ib + 640 * j];
            #pragma unroll
            for (int j = 0; j < JMAX; ++j) {
                reX[m][j] = fmaf(f[j].x, c0, reX[m][j]);
                imX[m][j] = fmaf(f[j].x, s0, imX[m][j]);
                reX[m][j] = fmaf(f[j].y, c1, reX[m][j]);
                imX[m][j] = fmaf(f[j].y, s1, imX[m][j]);
            }
            float nc0 = fmaf(c0, cd, -(s0 * sd));
            float ns0 = fmaf(s0, cd,  (c0 * sd));
            float nc1 = fmaf(c1, cd, -(s1 * sd));
            float ns1 = fmaf(s1, cd,  (c1 * sd));
            c0 = nc0; s0 = ns0; c1 = nc1; s1 = ns1;
            ++ib;
        }
    }

    // ---- per-frame: Hann combine in freq domain, magnitude, filterbank ----
    float2* __restrict__ myX   = &Xs[w][0];
    float*  __restrict__ mymag = &mags[w][0];

    for (int j = 0; j < JMAX; ++j) {
        const int t = w + 8 * j;
        if (t > 100) break;               // wave-uniform
        #pragma unroll
        for (int m = 0; m < 4; ++m) {
            const int k = m * 64 + lane;
            if (k < 202) myX[k] = make_float2(reX[m][j], imX[m][j]);
        }
        asm volatile("s_waitcnt lgkmcnt(0)" ::: "memory");   // same-wave DS order
        #pragma unroll
        for (int m = 0; m < 4; ++m) {
            const int k = m * 64 + lane;
            if (k <= 200) {
                float2 xm = (k == 0) ? myX[1] : myX[k - 1];
                float imm = (k == 0) ? -xm.y : xm.y;          // X[-1] = conj(X[1])
                float2 xq = myX[k + 1];
                float rw = 0.5f * reX[m][j] - 0.25f * (xm.x + xq.x);
                float iw = 0.5f * imX[m][j] - 0.25f * (imm  + xq.y);
                mymag[k] = sqrtf(rw * rw + iw * iw);
            }
        }
        asm volatile("s_waitcnt lgkmcnt(0)" ::: "memory");
        // filter channel c = lane: analytic triangle over [cks, cke]
        float acc = 0.0f;
        for (int k = cks; k <= cke; ++k) {
            float resp = 1.0f - fabsf(40.0f * (float)k - cctr) * cinv;
            acc = fmaf(resp, mymag[k], acc);
        }
        fbuf[lane * 101 + t] = acc;
    }
    __syncthreads();

    // ---- global LayerNorm over (c,t): two-pass mean/var ----
    float s = 0.0f;
    for (int i = tid; i < 6464; i += BLOCK) s += fbuf[i];
    #pragma unroll
    for (int off = 32; off > 0; off >>= 1) s += __shfl_down(s, off, 64);
    if (lane == 0) red[w] = s;
    __syncthreads();
    if (tid == 0) {
        float tsum = 0.0f;
        for (int i = 0; i < 8; ++i) tsum += red[i];
        stats[0] = tsum * (1.0f / 6464.0f);
    }
    __syncthreads();
    const float mu = stats[0];
    float v = 0.0f;
    for (int i = tid; i < 6464; i += BLOCK) { float d = fbuf[i] - mu; v = fmaf(d, d, v); }
    #pragma unroll
    for (int off = 32; off > 0; off >>= 1) v += __shfl_down(v, off, 64);
    if (lane == 0) red[w] = v;
    __syncthreads();
    if (tid == 0) {
        float tsum = 0.0f;
        for (int i = 0; i < 8; ++i) tsum += red[i];
        stats[1] = tsum * (1.0f / 6464.0f);
    }
    __syncthreads();
    const float var  = stats[1];
    const float isig = 1.0f / sqrtf(var + 1e-5f);

    // ---- log-energy + linear interp (101 -> 64) + transposed store ----
    // out[b, 0, t_out, c] = flat b*4096 + t_out*64 + c
    for (int idx = tid; idx < 4096; idx += BLOCK) {
        const int to = idx >> 6;
        const int c  = idx & 63;
        float pos = ((float)to + 0.5f) * 1.578125f - 0.5f;    // 101/64 exact
        pos = fminf(fmaxf(pos, 0.0f), 100.0f);
        int i0 = (int)floorf(pos);
        int i1 = i0 + 1; if (i1 > 100) i1 = 100;
        float fr = pos - (float)i0;
        float wc = ln_w[c], bc = ln_b[c];
        float x0 = fbuf[c * 101 + i0];
        float x1 = fbuf[c * 101 + i1];
        float y0 = fmaf(wc, (x0 - mu) * isig, bc);
        float y1 = fmaf(wc, (x1 - mu) * isig, bc);
        float l0 = log10f(fmaf(y0, y0, 1e-6f));
        float l1 = log10f(fmaf(y1, y1, 1e-6f));
        out[b * 4096 + idx] = l0 * (1.0f - fr) + l1 * fr;
    }
}

extern "C" void kernel_launch(void* const* d_in, const int* in_sizes, int n_in,
                              void* d_out, int out_size, void* d_ws, size_t ws_size,
                              hipStream_t stream)
{
    const float* wav = (const float*)d_in[0];
    const float* lo  = (const float*)d_in[1];
    const float* bd  = (const float*)d_in[2];
    const float* lw  = (const float*)d_in[3];
    const float* lb  = (const float*)d_in[4];
    float* out = (float*)d_out;

    // filters -> tail of d_out (after 1024*64*64 log-energy floats)
    fse_filters<<<(64 * 201 + 255) / 256, 256, 0, stream>>>(lo, bd, out + 1024 * 4096);
    // fused main pipeline: one block per batch item
    fse_main<<<1024, BLOCK, 0, stream>>>(wav, lo, bd, lw, lb, out);
}

// Round 2
// 568.947 us; speedup vs baseline: 1.1184x; 1.1184x over previous
//
#include <hip/hip_runtime.h>
#include <math.h>

#define BLOCK 512
#define JMAX 13

// ---------------------------------------------------------------------------
// Kernel 1: filters output (64 x 201), written to the tail of d_out.
// Mirrors _get_filters exactly in fp32.
// ---------------------------------------------------------------------------
__global__ void fse_filters(const float* __restrict__ low_hz_,
                            const float* __restrict__ band_hz_,
                            float* __restrict__ out)
{
    int idx = blockIdx.x * 256 + threadIdx.x;
    if (idx >= 64 * 201) return;
    int c = idx / 201;
    int k = idx - c * 201;
    float lo = 50.0f + fabsf(low_hz_[c]);
    float hi = lo + 50.0f + fabsf(band_hz_[c]);
    hi = fminf(fmaxf(hi, 50.0f), 8000.0f);
    float ctr = 0.5f * (lo + hi);
    float hbw = 0.5f * (hi - lo);
    float fq = 40.0f * (float)k;
    float resp = 1.0f - fabsf(fq - ctr) / hbw;
    out[idx] = (fq >= lo && fq <= hi) ? resp : 0.0f;
}

// ---------------------------------------------------------------------------
// Kernel 2: fully fused main pipeline. One block per batch item.
//  R2 change: the 4 bin-groups (m) are fused into ONE pass over the samples,
//  so each ds_read_b64 feeds 16 FMAs (was 4). DS instruction count /4.
// ---------------------------------------------------------------------------
__global__ __launch_bounds__(512, 2)
void fse_main(const float* __restrict__ wav,
              const float* __restrict__ low_hz_,
              const float* __restrict__ band_hz_,
              const float* __restrict__ ln_w,
              const float* __restrict__ ln_b,
              float* __restrict__ out)
{
    __shared__ float  xp[16400];        // reflect-padded waveform
    __shared__ float2 Xs[8][204];       // per-wave complex spectrum scratch
    __shared__ float  mags[8][204];     // per-wave magnitude scratch
    __shared__ float  fbuf[64 * 101];   // filtered[c][t]
    __shared__ float  fctr[64], finv[64];
    __shared__ int    fks[64], fke[64];
    __shared__ float  red[8];
    __shared__ float  stats[2];

    const int b    = blockIdx.x;
    const int tid  = threadIdx.x;
    const int w    = tid >> 6;      // wave id 0..7
    const int lane = tid & 63;
    const float* __restrict__ x = wav + b * 16000;

    // ---- stage waveform with reflect padding (pad=200 each side) ----
    for (int i = tid; i < 16400; i += BLOCK) {
        int p = i - 200;
        p = (p < 0) ? -p : p;
        p = (p > 15999) ? (31998 - p) : p;
        xp[i] = x[p];
    }

    // ---- per-channel filter params (thread c = tid < 64) ----
    if (tid < 64) {
        float lo = 50.0f + fabsf(low_hz_[tid]);
        float hi = lo + 50.0f + fabsf(band_hz_[tid]);
        hi = fminf(fmaxf(hi, 50.0f), 8000.0f);
        float ctr = 0.5f * (lo + hi);
        float hbw = 0.5f * (hi - lo);
        int ks = (int)ceilf(lo * 0.025f);
        if (ks < 0) ks = 0;
        while (40.0f * (float)ks < lo) ++ks;                     // match freq >= low
        while (ks > 0 && 40.0f * (float)(ks - 1) >= lo) --ks;
        int ke = (int)floorf(hi * 0.025f);
        if (ke > 200) ke = 200;
        while (40.0f * (float)ke > hi) --ke;                     // match freq <= high
        while (ke < 200 && 40.0f * (float)(ke + 1) <= hi) ++ke;
        fctr[tid] = ctr;
        finv[tid] = (hbw > 0.0f) ? (1.0f / hbw) : 0.0f;
        fks[tid]  = ks;
        fke[tid]  = ke;
    }
    __syncthreads();

    const float cctr = fctr[lane];
    const float cinv = finv[lane];
    const int   cks  = fks[lane];
    const int   cke  = fke[lane];

    // ---- DFT: wave w handles frames t = w + 8j (j = 0..12, clamped) ----
    // bins k = 64*m + lane for m = 0..3 (k <= 201 used), all 4 m fused.
    float reX[4][JMAX], imX[4][JMAX];
    const float2* __restrict__ xp2 = (const float2*)xp;

    float c0[4], s0[4], c1[4], s1[4], cd[4], sd[4];
    #pragma unroll
    for (int m = 0; m < 4; ++m) {
        const int k = m * 64 + lane;
        const float th = -0.015707963267948966f * (float)k;   // -2*pi*k/400
        sincosf(th, &s1[m], &c1[m]);            // phase at n=1
        sincosf(th + th, &sd[m], &cd[m]);       // step (2 samples per iter)
        c0[m] = 1.0f; s0[m] = 0.0f;             // phase at n=0
        #pragma unroll
        for (int j = 0; j < JMAX; ++j) { reX[m][j] = 0.0f; imX[m][j] = 0.0f; }
    }

    // j=12 would read past xp for waves >= 5 (results are discarded anyway);
    // clamp its offset so reads stay inside xp.
    const int o12 = (w < 5) ? 640 * 12 : 0;

    int ib = 80 * w;                  // float2 index of xp[160*w + n]/2
    #pragma unroll 2
    for (int h = 0; h < 200; ++h) {
        #pragma unroll
        for (int j = 0; j < JMAX; ++j) {
            const int off = (j == 12) ? o12 : 640 * j;
            float2 f = xp2[ib + off];
            #pragma unroll
            for (int m = 0; m < 4; ++m) {
                reX[m][j] = fmaf(f.x, c0[m], reX[m][j]);
                imX[m][j] = fmaf(f.x, s0[m], imX[m][j]);
                reX[m][j] = fmaf(f.y, c1[m], reX[m][j]);
                imX[m][j] = fmaf(f.y, s1[m], imX[m][j]);
            }
        }
        #pragma unroll
        for (int m = 0; m < 4; ++m) {
            float nc0 = fmaf(c0[m], cd[m], -(s0[m] * sd[m]));
            float ns0 = fmaf(s0[m], cd[m],  (c0[m] * sd[m]));
            float nc1 = fmaf(c1[m], cd[m], -(s1[m] * sd[m]));
            float ns1 = fmaf(s1[m], cd[m],  (c1[m] * sd[m]));
            c0[m] = nc0; s0[m] = ns0; c1[m] = nc1; s1[m] = ns1;
        }
        ++ib;
    }

    // ---- per-frame: Hann combine in freq domain, magnitude, filterbank ----
    float2* __restrict__ myX   = &Xs[w][0];
    float*  __restrict__ mymag = &mags[w][0];

    for (int j = 0; j < JMAX; ++j) {
        const int t = w + 8 * j;
        if (t > 100) break;               // wave-uniform
        #pragma unroll
        for (int m = 0; m < 4; ++m) {
            const int k = m * 64 + lane;
            if (k < 202) myX[k] = make_float2(reX[m][j], imX[m][j]);
        }
        asm volatile("s_waitcnt lgkmcnt(0)" ::: "memory");   // same-wave DS order
        #pragma unroll
        for (int m = 0; m < 4; ++m) {
            const int k = m * 64 + lane;
            if (k <= 200) {
                float2 xm = (k == 0) ? myX[1] : myX[k - 1];
                float imm = (k == 0) ? -xm.y : xm.y;          // X[-1] = conj(X[1])
                float2 xq = myX[k + 1];
                float rw = 0.5f * reX[m][j] - 0.25f * (xm.x + xq.x);
                float iw = 0.5f * imX[m][j] - 0.25f * (imm  + xq.y);
                mymag[k] = sqrtf(rw * rw + iw * iw);
            }
        }
        asm volatile("s_waitcnt lgkmcnt(0)" ::: "memory");
        // filter channel c = lane: analytic triangle over [cks, cke]
        float acc = 0.0f;
        for (int k = cks; k <= cke; ++k) {
            float resp = 1.0f - fabsf(40.0f * (float)k - cctr) * cinv;
            acc = fmaf(resp, mymag[k], acc);
        }
        fbuf[lane * 101 + t] = acc;
    }
    __syncthreads();

    // ---- global LayerNorm over (c,t): two-pass mean/var ----
    float s = 0.0f;
    for (int i = tid; i < 6464; i += BLOCK) s += fbuf[i];
    #pragma unroll
    for (int off = 32; off > 0; off >>= 1) s += __shfl_down(s, off, 64);
    if (lane == 0) red[w] = s;
    __syncthreads();
    if (tid == 0) {
        float tsum = 0.0f;
        for (int i = 0; i < 8; ++i) tsum += red[i];
        stats[0] = tsum * (1.0f / 6464.0f);
    }
    __syncthreads();
    const float mu = stats[0];
    float v = 0.0f;
    for (int i = tid; i < 6464; i += BLOCK) { float d = fbuf[i] - mu; v = fmaf(d, d, v); }
    #pragma unroll
    for (int off = 32; off > 0; off >>= 1) v += __shfl_down(v, off, 64);
    if (lane == 0) red[w] = v;
    __syncthreads();
    if (tid == 0) {
        float tsum = 0.0f;
        for (int i = 0; i < 8; ++i) tsum += red[i];
        stats[1] = tsum * (1.0f / 6464.0f);
    }
    __syncthreads();
    const float var  = stats[1];
    const float isig = 1.0f / sqrtf(var + 1e-5f);

    // ---- log-energy + linear interp (101 -> 64) + transposed store ----
    // out[b, 0, t_out, c] = flat b*4096 + t_out*64 + c
    for (int idx = tid; idx < 4096; idx += BLOCK) {
        const int to = idx >> 6;
        const int c  = idx & 63;
        float pos = ((float)to + 0.5f) * 1.578125f - 0.5f;    // 101/64 exact
        pos = fminf(fmaxf(pos, 0.0f), 100.0f);
        int i0 = (int)floorf(pos);
        int i1 = i0 + 1; if (i1 > 100) i1 = 100;
        float fr = pos - (float)i0;
        float wc = ln_w[c], bc = ln_b[c];
        float x0 = fbuf[c * 101 + i0];
        float x1 = fbuf[c * 101 + i1];
        float y0 = fmaf(wc, (x0 - mu) * isig, bc);
        float y1 = fmaf(wc, (x1 - mu) * isig, bc);
        float l0 = log10f(fmaf(y0, y0, 1e-6f));
        float l1 = log10f(fmaf(y1, y1, 1e-6f));
        out[b * 4096 + idx] = l0 * (1.0f - fr) + l1 * fr;
    }
}

extern "C" void kernel_launch(void* const* d_in, const int* in_sizes, int n_in,
                              void* d_out, int out_size, void* d_ws, size_t ws_size,
                              hipStream_t stream)
{
    const float* wav = (const float*)d_in[0];
    const float* lo  = (const float*)d_in[1];
    const float* bd  = (const float*)d_in[2];
    const float* lw  = (const float*)d_in[3];
    const float* lb  = (const float*)d_in[4];
    float* out = (float*)d_out;

    // filters -> tail of d_out (after 1024*64*64 log-energy floats)
    fse_filters<<<(64 * 201 + 255) / 256, 256, 0, stream>>>(lo, bd, out + 1024 * 4096);
    // fused main pipeline: one block per batch item
    fse_main<<<1024, BLOCK, 0, stream>>>(wav, lo, bd, lw, lb, out);
}

// Round 3
// 376.682 us; speedup vs baseline: 1.6892x; 1.5104x over previous
//
#include <hip/hip_runtime.h>
#include <math.h>

#define BLOCK 512
#define JMAX 13

typedef __attribute__((ext_vector_type(8))) short short8;
typedef __attribute__((ext_vector_type(16))) float f32x16;

__device__ inline unsigned short f2bf(float x) {
    unsigned u = __float_as_uint(x);
    unsigned r = u + 0x7fffu + ((u >> 16) & 1u);
    return (unsigned short)(r >> 16);
}

// ---------------------------------------------------------------------------
// Kernel 1: filters output (64 x 201) -> tail of d_out. Mirrors _get_filters.
// ---------------------------------------------------------------------------
__global__ void fse_filters(const float* __restrict__ low_hz_,
                            const float* __restrict__ band_hz_,
                            float* __restrict__ out)
{
    int idx = blockIdx.x * 256 + threadIdx.x;
    if (idx >= 64 * 201) return;
    int c = idx / 201;
    int k = idx - c * 201;
    float lo = 50.0f + fabsf(low_hz_[c]);
    float hi = lo + 50.0f + fabsf(band_hz_[c]);
    hi = fminf(fmaxf(hi, 50.0f), 8000.0f);
    float ctr = 0.5f * (lo + hi);
    float hbw = 0.5f * (hi - lo);
    float fq = 40.0f * (float)k;
    float resp = 1.0f - fabsf(fq - ctr) / hbw;
    out[idx] = (fq >= lo && fq <= hi) ? resp : 0.0f;
}

// ---------------------------------------------------------------------------
// Kernel 1b: build windowed-trig B^T (448 rows x 416 k), split bf16 hi/lo,
// into d_ws. Row j: j<=200 -> re bin j ; 224<=j<=424 -> im bin j-224 ; else 0.
// B[n][re k] = w[n] cos(2*pi*k*n/400), B[n][im k] = -w[n] sin(2*pi*k*n/400).
// Hann folded here => C = A x B is the windowed DFT directly.
// ---------------------------------------------------------------------------
__global__ void fse_setup_B(unsigned short* __restrict__ bh,
                            unsigned short* __restrict__ bl)
{
    int idx = blockIdx.x * 256 + threadIdx.x;   // j*416 + k
    if (idx >= 448 * 416) return;
    int j = idx / 416;
    int k = idx - j * 416;
    float v = 0.0f;
    if (k < 400) {
        int bin = -1, isim = 0;
        if (j <= 200) bin = j;
        else if (j >= 224 && j <= 424) { bin = j - 224; isim = 1; }
        if (bin >= 0) {
            int a = (bin * k) % 400;            // exact integer phase reduction
            float th = 6.283185307179586f * ((float)a / 400.0f);
            float sn, cs;
            sincosf(th, &sn, &cs);
            float wn = 0.5f - 0.5f * cosf(6.283185307179586f * ((float)k / 400.0f));
            v = isim ? (-wn * sn) : (wn * cs);
        }
    }
    unsigned short h = f2bf(v);
    float hf = __uint_as_float((unsigned)h << 16);
    unsigned short l = f2bf(v - hf);
    bh[idx] = h;
    bl[idx] = l;
}

// ---------------------------------------------------------------------------
// Kernel 2 (MFMA path): one block per batch item.
//  GEMM: C[128 x 448] = A[128 x 416] x B[416 x 448], split-2 bf16, 3 products.
//  A[t][n] = xp[160 t + n] (reflect-padded waveform in LDS, k>=400 zero-pad).
//  8 waves: mt = w>>1 (32 rows), nt-set = (w&1) ? im cols {7..13} : re {0..6}.
//  Shared-kappa fragments: A and B both read 16 contiguous bytes at
//  elem offset  s*16 + (lane>>5)*8 ; any shared k-permutation is correct.
//  C layout (HW-verified m74): col = lane&31, row = (r&3)+8*(r>>2)+4*(lane>>5).
// ---------------------------------------------------------------------------
__global__ __launch_bounds__(512, 2)
void fse_main_mfma(const float* __restrict__ wav,
                   const float* __restrict__ low_hz_,
                   const float* __restrict__ band_hz_,
                   const float* __restrict__ ln_w,
                   const float* __restrict__ ln_b,
                   const unsigned short* __restrict__ Bh,
                   const unsigned short* __restrict__ Bl,
                   float* __restrict__ out)
{
    // region1 (GEMM): xp 65664 | bsh 28672 | bsl 28672 | aph 8192 | apl 8192
    // region2 (post): mags [112][208] f32 93184 | fbuf 25856   (overlays r1)
    __shared__ __align__(16) char smem[139392];
    float*          xp  = (float*)smem;                     // [16416]
    unsigned short* bsh = (unsigned short*)(smem + 65664);  // [448][32]
    unsigned short* bsl = (unsigned short*)(smem + 94336);
    unsigned short* aph = (unsigned short*)(smem + 123008); // [128][32]
    unsigned short* apl = (unsigned short*)(smem + 131200);
    float*          mags = (float*)smem;                    // [112][208]
    float*          fbuf = (float*)(smem + 93184);          // [64*101]

    __shared__ float fctr[64], finv[64];
    __shared__ int   fks[64], fke[64];
    __shared__ float red[8];
    __shared__ float stats[2];

    const int b    = blockIdx.x;
    const int tid  = threadIdx.x;
    const int w    = tid >> 6;
    const int lane = tid & 63;
    const float* __restrict__ x = wav + b * 16000;

    // ---- stage waveform, reflect pad 200 each side, zero tail 16400..16415
    for (int i = tid; i < 16416; i += BLOCK) {
        float v = 0.0f;
        if (i < 16400) {
            int p = i - 200;
            p = (p < 0) ? -p : p;
            p = (p > 15999) ? (31998 - p) : p;
            v = x[p];
        }
        xp[i] = v;
    }

    // ---- per-channel filter params
    if (tid < 64) {
        float lo = 50.0f + fabsf(low_hz_[tid]);
        float hi = lo + 50.0f + fabsf(band_hz_[tid]);
        hi = fminf(fmaxf(hi, 50.0f), 8000.0f);
        float ctr = 0.5f * (lo + hi);
        float hbw = 0.5f * (hi - lo);
        int ks = (int)ceilf(lo * 0.025f);
        if (ks < 0) ks = 0;
        while (40.0f * (float)ks < lo) ++ks;
        while (ks > 0 && 40.0f * (float)(ks - 1) >= lo) --ks;
        int ke = (int)floorf(hi * 0.025f);
        if (ke > 200) ke = 200;
        while (40.0f * (float)ke > hi) --ke;
        while (ke < 200 && 40.0f * (float)(ke + 1) <= hi) ++ke;
        fctr[tid] = ctr;
        finv[tid] = (hbw > 0.0f) ? (1.0f / hbw) : 0.0f;
        fks[tid]  = ks;
        fke[tid]  = ke;
    }

    const int mt   = w >> 1;          // 0..3 : rows 32*mt .. 32*mt+31
    const int nt0  = (w & 1) ? 7 : 0; // col-tile base (re / im)
    const int jrow = lane & 31;
    const int g    = lane >> 5;
    const int ar   = mt * 32 + jrow;  // A row this lane loads

    f32x16 acc[7];
    #pragma unroll
    for (int n = 0; n < 7; ++n) {
        #pragma unroll
        for (int e = 0; e < 16; ++e) acc[n][e] = 0.0f;
    }

    // ---- K loop: 13 chunks of 32 (K padded 400->416 with zero B)
    for (int kc = 0; kc < 13; ++kc) {
        __syncthreads();   // prev compute done (and xp ready on kc==0)

        // stage B chunk: 448 rows x 32 k, hi+lo = 3584 x 16B, 7 per thread
        for (int u = tid; u < 3584; u += BLOCK) {
            int plane = (u >= 1792) ? 1 : 0;
            int rr    = u - plane * 1792;
            int row   = rr >> 2;
            int part  = rr & 3;
            const unsigned short* src = (plane ? Bl : Bh) + row * 416 + kc * 32 + part * 8;
            unsigned short*       dst = (plane ? bsl : bsh) + row * 32 + part * 8;
            *(uint4*)dst = *(const uint4*)src;
        }

        // stage A panel: 128 rows x 32 k -> bf16 hi/lo (t clamped to 100)
        {
            const int r   = tid >> 2;
            const int prt = tid & 3;
            const int te  = (r > 100) ? 100 : r;
            const float* s = xp + 160 * te + kc * 32 + prt * 8;
            float4 f0 = *(const float4*)s;
            float4 f1 = *(const float4*)(s + 4);
            float v[8] = {f0.x, f0.y, f0.z, f0.w, f1.x, f1.y, f1.z, f1.w};
            unsigned hh[4], ll[4];
            #pragma unroll
            for (int e = 0; e < 4; ++e) {
                unsigned short h0 = f2bf(v[2*e]),   h1 = f2bf(v[2*e+1]);
                float hf0 = __uint_as_float((unsigned)h0 << 16);
                float hf1 = __uint_as_float((unsigned)h1 << 16);
                unsigned short l0 = f2bf(v[2*e] - hf0), l1 = f2bf(v[2*e+1] - hf1);
                hh[e] = (unsigned)h0 | ((unsigned)h1 << 16);
                ll[e] = (unsigned)l0 | ((unsigned)l1 << 16);
            }
            *(uint4*)(aph + r * 32 + prt * 8) = make_uint4(hh[0], hh[1], hh[2], hh[3]);
            *(uint4*)(apl + r * 32 + prt * 8) = make_uint4(ll[0], ll[1], ll[2], ll[3]);
        }

        __syncthreads();   // staging visible

        #pragma unroll
        for (int s = 0; s < 2; ++s) {
            short8 Ah = *(const short8*)(aph + ar * 32 + s * 16 + g * 8);
            short8 Al = *(const short8*)(apl + ar * 32 + s * 16 + g * 8);
            #pragma unroll
            for (int n = 0; n < 7; ++n) {
                const int jj = (nt0 + n) * 32 + jrow;
                short8 Bhf = *(const short8*)(bsh + jj * 32 + s * 16 + g * 8);
                short8 Blf = *(const short8*)(bsl + jj * 32 + s * 16 + g * 8);
                acc[n] = __builtin_amdgcn_mfma_f32_32x32x16_bf16(Ah, Bhf, acc[n], 0, 0, 0);
                acc[n] = __builtin_amdgcn_mfma_f32_32x32x16_bf16(Ah, Blf, acc[n], 0, 0, 0);
                acc[n] = __builtin_amdgcn_mfma_f32_32x32x16_bf16(Al, Bhf, acc[n], 0, 0, 0);
            }
        }
    }

    __syncthreads();   // GEMM done; region1 memory now reusable as region2

    // ---- re waves write C_re to mags; then im waves fold sqrt(re^2+im^2)
    if (!(w & 1)) {
        #pragma unroll
        for (int n = 0; n < 7; ++n) {
            int k = n * 32 + jrow;
            if (k <= 200) {
                #pragma unroll
                for (int r = 0; r < 16; ++r) {
                    int t = mt * 32 + (r & 3) + 8 * (r >> 2) + 4 * g;
                    if (t <= 100) mags[t * 208 + k] = acc[n][r];
                }
            }
        }
    }
    __syncthreads();
    if (w & 1) {
        #pragma unroll
        for (int n = 0; n < 7; ++n) {
            int k = n * 32 + jrow;      // im bin = (nt-7)*32 + jrow
            if (k <= 200) {
                #pragma unroll
                for (int r = 0; r < 16; ++r) {
                    int t = mt * 32 + (r & 3) + 8 * (r >> 2) + 4 * g;
                    if (t <= 100) {
                        float re = mags[t * 208 + k];
                        float im = acc[n][r];
                        mags[t * 208 + k] = sqrtf(re * re + im * im);
                    }
                }
            }
        }
    }
    __syncthreads();

    // ---- filterbank: fbuf[c][t] = sum_k tri(c,k) * mags[t][k]
    const float cctr = fctr[lane];
    const float cinv = finv[lane];
    const int   cks  = fks[lane];
    const int   cke  = fke[lane];
    for (int j = 0; j < JMAX; ++j) {
        int t = w + 8 * j;
        if (t > 100) break;            // wave-uniform
        float a2 = 0.0f;
        for (int k = cks; k <= cke; ++k) {
            float resp = 1.0f - fabsf(40.0f * (float)k - cctr) * cinv;
            a2 = fmaf(resp, mags[t * 208 + k], a2);
        }
        fbuf[lane * 101 + t] = a2;
    }
    __syncthreads();

    // ---- global LayerNorm (two-pass)
    float s = 0.0f;
    for (int i = tid; i < 6464; i += BLOCK) s += fbuf[i];
    #pragma unroll
    for (int off = 32; off > 0; off >>= 1) s += __shfl_down(s, off, 64);
    if (lane == 0) red[w] = s;
    __syncthreads();
    if (tid == 0) {
        float tsum = 0.0f;
        for (int i = 0; i < 8; ++i) tsum += red[i];
        stats[0] = tsum * (1.0f / 6464.0f);
    }
    __syncthreads();
    const float mu = stats[0];
    float v = 0.0f;
    for (int i = tid; i < 6464; i += BLOCK) { float d = fbuf[i] - mu; v = fmaf(d, d, v); }
    #pragma unroll
    for (int off = 32; off > 0; off >>= 1) v += __shfl_down(v, off, 64);
    if (lane == 0) red[w] = v;
    __syncthreads();
    if (tid == 0) {
        float tsum = 0.0f;
        for (int i = 0; i < 8; ++i) tsum += red[i];
        stats[1] = tsum * (1.0f / 6464.0f);
    }
    __syncthreads();
    const float var  = stats[1];
    const float isig = 1.0f / sqrtf(var + 1e-5f);

    // ---- log-energy + interp 101->64 + transposed store
    for (int idx = tid; idx < 4096; idx += BLOCK) {
        const int to = idx >> 6;
        const int c  = idx & 63;
        float pos = ((float)to + 0.5f) * 1.578125f - 0.5f;
        pos = fminf(fmaxf(pos, 0.0f), 100.0f);
        int i0 = (int)floorf(pos);
        int i1 = i0 + 1; if (i1 > 100) i1 = 100;
        float fr = pos - (float)i0;
        float wc = ln_w[c], bc = ln_b[c];
        float x0 = fbuf[c * 101 + i0];
        float x1 = fbuf[c * 101 + i1];
        float y0 = fmaf(wc, (x0 - mu) * isig, bc);
        float y1 = fmaf(wc, (x1 - mu) * isig, bc);
        float l0 = log10f(fmaf(y0, y0, 1e-6f));
        float l1 = log10f(fmaf(y1, y1, 1e-6f));
        out[b * 4096 + idx] = l0 * (1.0f - fr) + l1 * fr;
    }
}

// ---------------------------------------------------------------------------
// Fallback (R2 VALU path) if ws_size is too small for the B table.
// ---------------------------------------------------------------------------
__global__ __launch_bounds__(512, 2)
void fse_main_valu(const float* __restrict__ wav,
                   const float* __restrict__ low_hz_,
                   const float* __restrict__ band_hz_,
                   const float* __restrict__ ln_w,
                   const float* __restrict__ ln_b,
                   float* __restrict__ out)
{
    __shared__ float  xp[16400];
    __shared__ float2 Xs[8][204];
    __shared__ float  mags[8][204];
    __shared__ float  fbuf[64 * 101];
    __shared__ float  fctr[64], finv[64];
    __shared__ int    fks[64], fke[64];
    __shared__ float  red[8];
    __shared__ float  stats[2];

    const int b    = blockIdx.x;
    const int tid  = threadIdx.x;
    const int w    = tid >> 6;
    const int lane = tid & 63;
    const float* __restrict__ x = wav + b * 16000;

    for (int i = tid; i < 16400; i += BLOCK) {
        int p = i - 200;
        p = (p < 0) ? -p : p;
        p = (p > 15999) ? (31998 - p) : p;
        xp[i] = x[p];
    }
    if (tid < 64) {
        float lo = 50.0f + fabsf(low_hz_[tid]);
        float hi = lo + 50.0f + fabsf(band_hz_[tid]);
        hi = fminf(fmaxf(hi, 50.0f), 8000.0f);
        float ctr = 0.5f * (lo + hi);
        float hbw = 0.5f * (hi - lo);
        int ks = (int)ceilf(lo * 0.025f);
        if (ks < 0) ks = 0;
        while (40.0f * (float)ks < lo) ++ks;
        while (ks > 0 && 40.0f * (float)(ks - 1) >= lo) --ks;
        int ke = (int)floorf(hi * 0.025f);
        if (ke > 200) ke = 200;
        while (40.0f * (float)ke > hi) --ke;
        while (ke < 200 && 40.0f * (float)(ke + 1) <= hi) ++ke;
        fctr[tid] = ctr;
        finv[tid] = (hbw > 0.0f) ? (1.0f / hbw) : 0.0f;
        fks[tid]  = ks;
        fke[tid]  = ke;
    }
    __syncthreads();

    const float cctr = fctr[lane];
    const float cinv = finv[lane];
    const int   cks  = fks[lane];
    const int   cke  = fke[lane];

    float reX[4][JMAX], imX[4][JMAX];
    const float2* __restrict__ xp2 = (const float2*)xp;
    float c0[4], s0[4], c1[4], s1[4], cd[4], sd[4];
    #pragma unroll
    for (int m = 0; m < 4; ++m) {
        const int k = m * 64 + lane;
        const float th = -0.015707963267948966f * (float)k;
        sincosf(th, &s1[m], &c1[m]);
        sincosf(th + th, &sd[m], &cd[m]);
        c0[m] = 1.0f; s0[m] = 0.0f;
        #pragma unroll
        for (int j = 0; j < JMAX; ++j) { reX[m][j] = 0.0f; imX[m][j] = 0.0f; }
    }
    const int o12 = (w < 5) ? 640 * 12 : 0;
    int ib = 80 * w;
    #pragma unroll 2
    for (int h = 0; h < 200; ++h) {
        #pragma unroll
        for (int j = 0; j < JMAX; ++j) {
            const int off = (j == 12) ? o12 : 640 * j;
            float2 f = xp2[ib + off];
            #pragma unroll
            for (int m = 0; m < 4; ++m) {
                reX[m][j] = fmaf(f.x, c0[m], reX[m][j]);
                imX[m][j] = fmaf(f.x, s0[m], imX[m][j]);
                reX[m][j] = fmaf(f.y, c1[m], reX[m][j]);
                imX[m][j] = fmaf(f.y, s1[m], imX[m][j]);
            }
        }
        #pragma unroll
        for (int m = 0; m < 4; ++m) {
            float nc0 = fmaf(c0[m], cd[m], -(s0[m] * sd[m]));
            float ns0 = fmaf(s0[m], cd[m],  (c0[m] * sd[m]));
            float nc1 = fmaf(c1[m], cd[m], -(s1[m] * sd[m]));
            float ns1 = fmaf(s1[m], cd[m],  (c1[m] * sd[m]));
            c0[m] = nc0; s0[m] = ns0; c1[m] = nc1; s1[m] = ns1;
        }
        ++ib;
    }

    float2* __restrict__ myX   = &Xs[w][0];
    float*  __restrict__ mymag = &mags[w][0];
    for (int j = 0; j < JMAX; ++j) {
        const int t = w + 8 * j;
        if (t > 100) break;
        #pragma unroll
        for (int m = 0; m < 4; ++m) {
            const int k = m * 64 + lane;
            if (k < 202) myX[k] = make_float2(reX[m][j], imX[m][j]);
        }
        asm volatile("s_waitcnt lgkmcnt(0)" ::: "memory");
        #pragma unroll
        for (int m = 0; m < 4; ++m) {
            const int k = m * 64 + lane;
            if (k <= 200) {
                float2 xm = (k == 0) ? myX[1] : myX[k - 1];
                float imm = (k == 0) ? -xm.y : xm.y;
                float2 xq = myX[k + 1];
                float rw = 0.5f * reX[m][j] - 0.25f * (xm.x + xq.x);
                float iw = 0.5f * imX[m][j] - 0.25f * (imm  + xq.y);
                mymag[k] = sqrtf(rw * rw + iw * iw);
            }
        }
        asm volatile("s_waitcnt lgkmcnt(0)" ::: "memory");
        float acc = 0.0f;
        for (int k = cks; k <= cke; ++k) {
            float resp = 1.0f - fabsf(40.0f * (float)k - cctr) * cinv;
            acc = fmaf(resp, mymag[k], acc);
        }
        fbuf[lane * 101 + t] = acc;
    }
    __syncthreads();

    float s = 0.0f;
    for (int i = tid; i < 6464; i += BLOCK) s += fbuf[i];
    #pragma unroll
    for (int off = 32; off > 0; off >>= 1) s += __shfl_down(s, off, 64);
    if (lane == 0) red[w] = s;
    __syncthreads();
    if (tid == 0) {
        float tsum = 0.0f;
        for (int i = 0; i < 8; ++i) tsum += red[i];
        stats[0] = tsum * (1.0f / 6464.0f);
    }
    __syncthreads();
    const float mu = stats[0];
    float v = 0.0f;
    for (int i = tid; i < 6464; i += BLOCK) { float d = fbuf[i] - mu; v = fmaf(d, d, v); }
    #pragma unroll
    for (int off = 32; off > 0; off >>= 1) v += __shfl_down(v, off, 64);
    if (lane == 0) red[w] = v;
    __syncthreads();
    if (tid == 0) {
        float tsum = 0.0f;
        for (int i = 0; i < 8; ++i) tsum += red[i];
        stats[1] = tsum * (1.0f / 6464.0f);
    }
    __syncthreads();
    const float var  = stats[1];
    const float isig = 1.0f / sqrtf(var + 1e-5f);

    for (int idx = tid; idx < 4096; idx += BLOCK) {
        const int to = idx >> 6;
        const int c  = idx & 63;
        float pos = ((float)to + 0.5f) * 1.578125f - 0.5f;
        pos = fminf(fmaxf(pos, 0.0f), 100.0f);
        int i0 = (int)floorf(pos);
        int i1 = i0 + 1; if (i1 > 100) i1 = 100;
        float fr = pos - (float)i0;
        float wc = ln_w[c], bc = ln_b[c];
        float x0 = fbuf[c * 101 + i0];
        float x1 = fbuf[c * 101 + i1];
        float y0 = fmaf(wc, (x0 - mu) * isig, bc);
        float y1 = fmaf(wc, (x1 - mu) * isig, bc);
        float l0 = log10f(fmaf(y0, y0, 1e-6f));
        float l1 = log10f(fmaf(y1, y1, 1e-6f));
        out[b * 4096 + idx] = l0 * (1.0f - fr) + l1 * fr;
    }
}

extern "C" void kernel_launch(void* const* d_in, const int* in_sizes, int n_in,
                              void* d_out, int out_size, void* d_ws, size_t ws_size,
                              hipStream_t stream)
{
    const float* wav = (const float*)d_in[0];
    const float* lo  = (const float*)d_in[1];
    const float* bd  = (const float*)d_in[2];
    const float* lw  = (const float*)d_in[3];
    const float* lb  = (const float*)d_in[4];
    float* out = (float*)d_out;

    fse_filters<<<(64 * 201 + 255) / 256, 256, 0, stream>>>(lo, bd, out + 1024 * 4096);

    const size_t BNEED = (size_t)448 * 416 * 2 * sizeof(unsigned short); // 745472 B
    if (ws_size >= BNEED) {
        unsigned short* Bh = (unsigned short*)d_ws;
        unsigned short* Bl = Bh + 448 * 416;
        fse_setup_B<<<(448 * 416 + 255) / 256, 256, 0, stream>>>(Bh, Bl);
        fse_main_mfma<<<1024, BLOCK, 0, stream>>>(wav, lo, bd, lw, lb, Bh, Bl, out);
    } else {
        fse_main_valu<<<1024, BLOCK, 0, stream>>>(wav, lo, bd, lw, lb, out);
    }
}

// Round 4
// 246.481 us; speedup vs baseline: 2.5815x; 1.5282x over previous
//
#include <hip/hip_runtime.h>
#include <math.h>

#define BLOCK 512
#define JMAX 13

typedef __attribute__((ext_vector_type(8))) short short8;
typedef __attribute__((ext_vector_type(16))) float f32x16;
typedef __attribute__((ext_vector_type(4))) unsigned uint4v;

__device__ inline unsigned short f2bf(float x) {
    unsigned u = __float_as_uint(x);
    unsigned r = u + 0x7fffu + ((u >> 16) & 1u);
    return (unsigned short)(r >> 16);
}

// ---------------------------------------------------------------------------
// Kernel 1: filters output (64 x 201) -> tail of d_out. Mirrors _get_filters.
// ---------------------------------------------------------------------------
__global__ void fse_filters(const float* __restrict__ low_hz_,
                            const float* __restrict__ band_hz_,
                            float* __restrict__ out)
{
    int idx = blockIdx.x * 256 + threadIdx.x;
    if (idx >= 64 * 201) return;
    int c = idx / 201;
    int k = idx - c * 201;
    float lo = 50.0f + fabsf(low_hz_[c]);
    float hi = lo + 50.0f + fabsf(band_hz_[c]);
    hi = fminf(fmaxf(hi, 50.0f), 8000.0f);
    float ctr = 0.5f * (lo + hi);
    float hbw = 0.5f * (hi - lo);
    float fq = 40.0f * (float)k;
    float resp = 1.0f - fabsf(fq - ctr) / hbw;
    out[idx] = (fq >= lo && fq <= hi) ? resp : 0.0f;
}

// ---------------------------------------------------------------------------
// Kernel 1b: build B in chunk-linear layout: Bt[kc][pl][part][row][8] bf16.
//   row j: j<=200 -> re bin j ; 224<=j<=424 -> im bin j-224 ; else 0.
//   value = w[n] cos(2 pi bin n/400)  (re)  or  -w[n] sin(...) (im),
//   n = kc*32 + part*8 + e, Hann folded in. pl=0: hi bf16, pl=1: lo residual.
//   This layout makes per-kc LDS staging a LINEAR coalesced copy and wave
//   fragment reads consecutive-16B-per-lane (bank-conflict-free).
// ---------------------------------------------------------------------------
__global__ void fse_setup_B(unsigned short* __restrict__ bt)
{
    int idx = blockIdx.x * 256 + threadIdx.x;   // 13*2*4*448*8 = 372736
    if (idx >= 372736) return;
    int e   = idx & 7;
    int t   = idx >> 3;
    int row = t % 448;
    int q   = t / 448;          // ((kc*2 + pl)*4 + p)
    int p   = q & 3;
    int pl  = (q >> 2) & 1;
    int kc  = q >> 3;
    int n   = kc * 32 + p * 8 + e;
    float v = 0.0f;
    if (n < 400) {
        int bin = -1, isim = 0;
        if (row <= 200) bin = row;
        else if (row >= 224 && row <= 424) { bin = row - 224; isim = 1; }
        if (bin >= 0) {
            int a = (bin * n) % 400;            // exact integer phase reduction
            float th = 6.283185307179586f * ((float)a / 400.0f);
            float sn, cs;
            sincosf(th, &sn, &cs);
            float wn = 0.5f - 0.5f * cosf(6.283185307179586f * ((float)n / 400.0f));
            v = isim ? (-wn * sn) : (wn * cs);
        }
    }
    unsigned short h = f2bf(v);
    float hf = __uint_as_float((unsigned)h << 16);
    unsigned short l = f2bf(v - hf);
    bt[idx] = pl ? l : h;
}

// ---------------------------------------------------------------------------
// Kernel 2 (MFMA path): one block per batch item.
//  C[128 x 448] = A[128 x 416] x B[416 x 448], split-2 bf16 (3 products).
//  - B: double-buffered LDS, chunk-linear layout, T14 staging (issue loads
//    before compute, ds_write after, ONE barrier per kc).
//  - A: per-lane directly from global (VMEM pipe; no LDS round-trip),
//    reflect handled scalar on edge rows only; in-register hi/lo split.
//  - fragment reads: consecutive 16B per lane -> conflict-free.
//  C layout (HW-verified m74): col = lane&31, row = (r&3)+8*(r>>2)+4*(lane>>5).
// ---------------------------------------------------------------------------
__global__ __launch_bounds__(512, 2)
void fse_main_mfma(const float* __restrict__ wav,
                   const float* __restrict__ low_hz_,
                   const float* __restrict__ band_hz_,
                   const float* __restrict__ ln_w,
                   const float* __restrict__ ln_b,
                   const unsigned short* __restrict__ Bt,
                   float* __restrict__ out)
{
    // [0, 57344)       B buffer 0          (GEMM phase)
    // [57344, 114688)  B buffer 1          (GEMM phase)
    // [0, 84032)       mags[101][208] f32  (post phase, overlays)
    // [84032, 109888)  fbuf[64*101]  f32   (post phase, overlays buf1)
    __shared__ __align__(16) char smem[114688];
    float* mags = (float*)smem;
    float* fbuf = (float*)(smem + 84032);

    __shared__ float fctr[64], finv[64];
    __shared__ int   fks[64], fke[64];
    __shared__ float red[8];
    __shared__ float stats[2];

    const int b    = blockIdx.x;
    const int tid  = threadIdx.x;
    const int w    = tid >> 6;
    const int lane = tid & 63;
    const float* __restrict__ x = wav + b * 16000;

    // ---- per-channel filter params
    if (tid < 64) {
        float lo = 50.0f + fabsf(low_hz_[tid]);
        float hi = lo + 50.0f + fabsf(band_hz_[tid]);
        hi = fminf(fmaxf(hi, 50.0f), 8000.0f);
        float ctr = 0.5f * (lo + hi);
        float hbw = 0.5f * (hi - lo);
        int ks = (int)ceilf(lo * 0.025f);
        if (ks < 0) ks = 0;
        while (40.0f * (float)ks < lo) ++ks;
        while (ks > 0 && 40.0f * (float)(ks - 1) >= lo) --ks;
        int ke = (int)floorf(hi * 0.025f);
        if (ke > 200) ke = 200;
        while (40.0f * (float)ke > hi) --ke;
        while (ke < 200 && 40.0f * (float)(ke + 1) <= hi) ++ke;
        fctr[tid] = ctr;
        finv[tid] = (hbw > 0.0f) ? (1.0f / hbw) : 0.0f;
        fks[tid]  = ks;
        fke[tid]  = ke;
    }

    const int mt   = w >> 1;          // m-tile: rows 32*mt .. 32*mt+31
    const int half = w & 1;           // 0: re cols, 1: im cols
    const int jrow = lane & 31;
    const int g    = lane >> 5;
    const int arow = mt * 32 + jrow;
    const int te   = (arow <= 100) ? arow : 50;   // discarded rows -> safe interior

    const uint4* __restrict__ btg = (const uint4*)Bt;   // 3584 uint4 per kc

    // ---- prologue: stage kc=0 into buffer 0
    {
        uint4 rr[7];
        #pragma unroll
        for (int i = 0; i < 7; ++i) rr[i] = btg[i * 512 + tid];
        uint4* dst = (uint4*)smem;
        #pragma unroll
        for (int i = 0; i < 7; ++i) dst[i * 512 + tid] = rr[i];
    }
    __syncthreads();

    f32x16 acc[7];
    #pragma unroll
    for (int n = 0; n < 7; ++n) {
        #pragma unroll
        for (int e = 0; e < 16; ++e) acc[n][e] = 0.0f;
    }

    int curoff = 0;
    for (int kc = 0; kc < 13; ++kc) {
        uint4 rr[7];
        const bool pre = (kc < 12);
        if (pre) {
            const uint4* src = btg + (kc + 1) * 3584;
            #pragma unroll
            for (int i = 0; i < 7; ++i) rr[i] = src[i * 512 + tid];
        }
        const unsigned short* bs = (const unsigned short*)(smem + curoff);

        #pragma unroll
        for (int s = 0; s < 2; ++s) {
            // A fragment: 8 floats from global, reflect on edges
            float v8[8];
            int i0 = 160 * te - 200 + kc * 32 + s * 16 + g * 8;
            if (i0 >= 0 && i0 <= 15992) {
                float4 a0 = *(const float4*)(x + i0);
                float4 a1 = *(const float4*)(x + i0 + 4);
                v8[0] = a0.x; v8[1] = a0.y; v8[2] = a0.z; v8[3] = a0.w;
                v8[4] = a1.x; v8[5] = a1.y; v8[6] = a1.z; v8[7] = a1.w;
            } else {
                #pragma unroll
                for (int e = 0; e < 8; ++e) {
                    int p = i0 + e;
                    p = (p < 0) ? -p : p;
                    p = (p > 15999) ? (31998 - p) : p;
                    v8[e] = x[p];
                }
            }
            // in-register split to bf16 hi/lo
            uint4v ah, al;
            #pragma unroll
            for (int qq = 0; qq < 4; ++qq) {
                unsigned short h0 = f2bf(v8[2*qq]),   h1 = f2bf(v8[2*qq+1]);
                float hf0 = __uint_as_float((unsigned)h0 << 16);
                float hf1 = __uint_as_float((unsigned)h1 << 16);
                unsigned short l0 = f2bf(v8[2*qq] - hf0), l1 = f2bf(v8[2*qq+1] - hf1);
                ah[qq] = (unsigned)h0 | ((unsigned)h1 << 16);
                al[qq] = (unsigned)l0 | ((unsigned)l1 << 16);
            }
            short8 Ah = __builtin_bit_cast(short8, ah);
            short8 Al = __builtin_bit_cast(short8, al);

            const int pb = (s * 2 + g) * 448;      // part base (rows)
            #pragma unroll
            for (int n = 0; n < 7; ++n) {
                const int ro = (half * 7 + n) * 32 + jrow;
                short8 Bh = *(const short8*)(bs + (pb + ro) * 8);
                short8 Bl = *(const short8*)(bs + (1792 * 8) + (pb + ro) * 8);
                acc[n] = __builtin_amdgcn_mfma_f32_32x32x16_bf16(Ah, Bh, acc[n], 0, 0, 0);
                acc[n] = __builtin_amdgcn_mfma_f32_32x32x16_bf16(Ah, Bl, acc[n], 0, 0, 0);
                acc[n] = __builtin_amdgcn_mfma_f32_32x32x16_bf16(Al, Bh, acc[n], 0, 0, 0);
            }
        }

        if (pre) {
            uint4* dst = (uint4*)(smem + (curoff ^ 57344));
            #pragma unroll
            for (int i = 0; i < 7; ++i) dst[i * 512 + tid] = rr[i];
        }
        __syncthreads();
        curoff ^= 57344;
    }

    // ---- epilogue: re waves write C_re; im waves fold sqrt(re^2+im^2)
    if (half == 0) {
        #pragma unroll
        for (int n = 0; n < 7; ++n) {
            int k = n * 32 + jrow;
            if (k <= 200) {
                #pragma unroll
                for (int r = 0; r < 16; ++r) {
                    int t = mt * 32 + (r & 3) + 8 * (r >> 2) + 4 * g;
                    if (t <= 100) mags[t * 208 + k] = acc[n][r];
                }
            }
        }
    }
    __syncthreads();
    if (half == 1) {
        #pragma unroll
        for (int n = 0; n < 7; ++n) {
            int k = n * 32 + jrow;
            if (k <= 200) {
                #pragma unroll
                for (int r = 0; r < 16; ++r) {
                    int t = mt * 32 + (r & 3) + 8 * (r >> 2) + 4 * g;
                    if (t <= 100) {
                        float re = mags[t * 208 + k];
                        float im = acc[n][r];
                        mags[t * 208 + k] = sqrtf(re * re + im * im);
                    }
                }
            }
        }
    }
    __syncthreads();

    // ---- filterbank: fbuf[c][t] = sum_k tri(c,k) * mags[t][k]
    const float cctr = fctr[lane];
    const float cinv = finv[lane];
    const int   cks  = fks[lane];
    const int   cke  = fke[lane];
    for (int j = 0; j < JMAX; ++j) {
        int t = w + 8 * j;
        if (t > 100) break;            // wave-uniform
        float a2 = 0.0f;
        for (int k = cks; k <= cke; ++k) {
            float resp = 1.0f - fabsf(40.0f * (float)k - cctr) * cinv;
            a2 = fmaf(resp, mags[t * 208 + k], a2);
        }
        fbuf[lane * 101 + t] = a2;
    }
    __syncthreads();

    // ---- global LayerNorm (two-pass)
    float s = 0.0f;
    for (int i = tid; i < 6464; i += BLOCK) s += fbuf[i];
    #pragma unroll
    for (int off = 32; off > 0; off >>= 1) s += __shfl_down(s, off, 64);
    if (lane == 0) red[w] = s;
    __syncthreads();
    if (tid == 0) {
        float tsum = 0.0f;
        for (int i = 0; i < 8; ++i) tsum += red[i];
        stats[0] = tsum * (1.0f / 6464.0f);
    }
    __syncthreads();
    const float mu = stats[0];
    float v = 0.0f;
    for (int i = tid; i < 6464; i += BLOCK) { float d = fbuf[i] - mu; v = fmaf(d, d, v); }
    #pragma unroll
    for (int off = 32; off > 0; off >>= 1) v += __shfl_down(v, off, 64);
    if (lane == 0) red[w] = v;
    __syncthreads();
    if (tid == 0) {
        float tsum = 0.0f;
        for (int i = 0; i < 8; ++i) tsum += red[i];
        stats[1] = tsum * (1.0f / 6464.0f);
    }
    __syncthreads();
    const float var  = stats[1];
    const float isig = 1.0f / sqrtf(var + 1e-5f);

    // ---- log-energy + interp 101->64 + transposed store
    for (int idx = tid; idx < 4096; idx += BLOCK) {
        const int to = idx >> 6;
        const int c  = idx & 63;
        float pos = ((float)to + 0.5f) * 1.578125f - 0.5f;
        pos = fminf(fmaxf(pos, 0.0f), 100.0f);
        int i0 = (int)floorf(pos);
        int i1 = i0 + 1; if (i1 > 100) i1 = 100;
        float fr = pos - (float)i0;
        float wc = ln_w[c], bc = ln_b[c];
        float x0 = fbuf[c * 101 + i0];
        float x1 = fbuf[c * 101 + i1];
        float y0 = fmaf(wc, (x0 - mu) * isig, bc);
        float y1 = fmaf(wc, (x1 - mu) * isig, bc);
        float l0 = log10f(fmaf(y0, y0, 1e-6f));
        float l1 = log10f(fmaf(y1, y1, 1e-6f));
        out[b * 4096 + idx] = l0 * (1.0f - fr) + l1 * fr;
    }
}

// ---------------------------------------------------------------------------
// Fallback (R2 VALU path) if ws_size is too small for the B table.
// ---------------------------------------------------------------------------
__global__ __launch_bounds__(512, 2)
void fse_main_valu(const float* __restrict__ wav,
                   const float* __restrict__ low_hz_,
                   const float* __restrict__ band_hz_,
                   const float* __restrict__ ln_w,
                   const float* __restrict__ ln_b,
                   float* __restrict__ out)
{
    __shared__ float  xp[16400];
    __shared__ float2 Xs[8][204];
    __shared__ float  mags[8][204];
    __shared__ float  fbuf[64 * 101];
    __shared__ float  fctr[64], finv[64];
    __shared__ int    fks[64], fke[64];
    __shared__ float  red[8];
    __shared__ float  stats[2];

    const int b    = blockIdx.x;
    const int tid  = threadIdx.x;
    const int w    = tid >> 6;
    const int lane = tid & 63;
    const float* __restrict__ x = wav + b * 16000;

    for (int i = tid; i < 16400; i += BLOCK) {
        int p = i - 200;
        p = (p < 0) ? -p : p;
        p = (p > 15999) ? (31998 - p) : p;
        xp[i] = x[p];
    }
    if (tid < 64) {
        float lo = 50.0f + fabsf(low_hz_[tid]);
        float hi = lo + 50.0f + fabsf(band_hz_[tid]);
        hi = fminf(fmaxf(hi, 50.0f), 8000.0f);
        float ctr = 0.5f * (lo + hi);
        float hbw = 0.5f * (hi - lo);
        int ks = (int)ceilf(lo * 0.025f);
        if (ks < 0) ks = 0;
        while (40.0f * (float)ks < lo) ++ks;
        while (ks > 0 && 40.0f * (float)(ks - 1) >= lo) --ks;
        int ke = (int)floorf(hi * 0.025f);
        if (ke > 200) ke = 200;
        while (40.0f * (float)ke > hi) --ke;
        while (ke < 200 && 40.0f * (float)(ke + 1) <= hi) ++ke;
        fctr[tid] = ctr;
        finv[tid] = (hbw > 0.0f) ? (1.0f / hbw) : 0.0f;
        fks[tid]  = ks;
        fke[tid]  = ke;
    }
    __syncthreads();

    const float cctr = fctr[lane];
    const float cinv = finv[lane];
    const int   cks  = fks[lane];
    const int   cke  = fke[lane];

    float reX[4][JMAX], imX[4][JMAX];
    const float2* __restrict__ xp2 = (const float2*)xp;
    float c0[4], s0[4], c1[4], s1[4], cd[4], sd[4];
    #pragma unroll
    for (int m = 0; m < 4; ++m) {
        const int k = m * 64 + lane;
        const float th = -0.015707963267948966f * (float)k;
        sincosf(th, &s1[m], &c1[m]);
        sincosf(th + th, &sd[m], &cd[m]);
        c0[m] = 1.0f; s0[m] = 0.0f;
        #pragma unroll
        for (int j = 0; j < JMAX; ++j) { reX[m][j] = 0.0f; imX[m][j] = 0.0f; }
    }
    const int o12 = (w < 5) ? 640 * 12 : 0;
    int ib = 80 * w;
    #pragma unroll 2
    for (int h = 0; h < 200; ++h) {
        #pragma unroll
        for (int j = 0; j < JMAX; ++j) {
            const int off = (j == 12) ? o12 : 640 * j;
            float2 f = xp2[ib + off];
            #pragma unroll
            for (int m = 0; m < 4; ++m) {
                reX[m][j] = fmaf(f.x, c0[m], reX[m][j]);
                imX[m][j] = fmaf(f.x, s0[m], imX[m][j]);
                reX[m][j] = fmaf(f.y, c1[m], reX[m][j]);
                imX[m][j] = fmaf(f.y, s1[m], imX[m][j]);
            }
        }
        #pragma unroll
        for (int m = 0; m < 4; ++m) {
            float nc0 = fmaf(c0[m], cd[m], -(s0[m] * sd[m]));
            float ns0 = fmaf(s0[m], cd[m],  (c0[m] * sd[m]));
            float nc1 = fmaf(c1[m], cd[m], -(s1[m] * sd[m]));
            float ns1 = fmaf(s1[m], cd[m],  (c1[m] * sd[m]));
            c0[m] = nc0; s0[m] = ns0; c1[m] = nc1; s1[m] = ns1;
        }
        ++ib;
    }

    float2* __restrict__ myX   = &Xs[w][0];
    float*  __restrict__ mymag = &mags[w][0];
    for (int j = 0; j < JMAX; ++j) {
        const int t = w + 8 * j;
        if (t > 100) break;
        #pragma unroll
        for (int m = 0; m < 4; ++m) {
            const int k = m * 64 + lane;
            if (k < 202) myX[k] = make_float2(reX[m][j], imX[m][j]);
        }
        asm volatile("s_waitcnt lgkmcnt(0)" ::: "memory");
        #pragma unroll
        for (int m = 0; m < 4; ++m) {
            const int k = m * 64 + lane;
            if (k <= 200) {
                float2 xm = (k == 0) ? myX[1] : myX[k - 1];
                float imm = (k == 0) ? -xm.y : xm.y;
                float2 xq = myX[k + 1];
                float rw = 0.5f * reX[m][j] - 0.25f * (xm.x + xq.x);
                float iw = 0.5f * imX[m][j] - 0.25f * (imm  + xq.y);
                mymag[k] = sqrtf(rw * rw + iw * iw);
            }
        }
        asm volatile("s_waitcnt lgkmcnt(0)" ::: "memory");
        float acc = 0.0f;
        for (int k = cks; k <= cke; ++k) {
            float resp = 1.0f - fabsf(40.0f * (float)k - cctr) * cinv;
            acc = fmaf(resp, mymag[k], acc);
        }
        fbuf[lane * 101 + t] = acc;
    }
    __syncthreads();

    float s = 0.0f;
    for (int i = tid; i < 6464; i += BLOCK) s += fbuf[i];
    #pragma unroll
    for (int off = 32; off > 0; off >>= 1) s += __shfl_down(s, off, 64);
    if (lane == 0) red[w] = s;
    __syncthreads();
    if (tid == 0) {
        float tsum = 0.0f;
        for (int i = 0; i < 8; ++i) tsum += red[i];
        stats[0] = tsum * (1.0f / 6464.0f);
    }
    __syncthreads();
    const float mu = stats[0];
    float v = 0.0f;
    for (int i = tid; i < 6464; i += BLOCK) { float d = fbuf[i] - mu; v = fmaf(d, d, v); }
    #pragma unroll
    for (int off = 32; off > 0; off >>= 1) v += __shfl_down(v, off, 64);
    if (lane == 0) red[w] = v;
    __syncthreads();
    if (tid == 0) {
        float tsum = 0.0f;
        for (int i = 0; i < 8; ++i) tsum += red[i];
        stats[1] = tsum * (1.0f / 6464.0f);
    }
    __syncthreads();
    const float var  = stats[1];
    const float isig = 1.0f / sqrtf(var + 1e-5f);

    for (int idx = tid; idx < 4096; idx += BLOCK) {
        const int to = idx >> 6;
        const int c  = idx & 63;
        float pos = ((float)to + 0.5f) * 1.578125f - 0.5f;
        pos = fminf(fmaxf(pos, 0.0f), 100.0f);
        int i0 = (int)floorf(pos);
        int i1 = i0 + 1; if (i1 > 100) i1 = 100;
        float fr = pos - (float)i0;
        float wc = ln_w[c], bc = ln_b[c];
        float x0 = fbuf[c * 101 + i0];
        float x1 = fbuf[c * 101 + i1];
        float y0 = fmaf(wc, (x0 - mu) * isig, bc);
        float y1 = fmaf(wc, (x1 - mu) * isig, bc);
        float l0 = log10f(fmaf(y0, y0, 1e-6f));
        float l1 = log10f(fmaf(y1, y1, 1e-6f));
        out[b * 4096 + idx] = l0 * (1.0f - fr) + l1 * fr;
    }
}

extern "C" void kernel_launch(void* const* d_in, const int* in_sizes, int n_in,
                              void* d_out, int out_size, void* d_ws, size_t ws_size,
                              hipStream_t stream)
{
    const float* wav = (const float*)d_in[0];
    const float* lo  = (const float*)d_in[1];
    const float* bd  = (const float*)d_in[2];
    const float* lw  = (const float*)d_in[3];
    const float* lb  = (const float*)d_in[4];
    float* out = (float*)d_out;

    fse_filters<<<(64 * 201 + 255) / 256, 256, 0, stream>>>(lo, bd, out + 1024 * 4096);

    const size_t BNEED = (size_t)372736 * sizeof(unsigned short); // 745472 B
    if (ws_size >= BNEED) {
        unsigned short* Bts = (unsigned short*)d_ws;
        fse_setup_B<<<(372736 + 255) / 256, 256, 0, stream>>>(Bts);
        fse_main_mfma<<<1024, BLOCK, 0, stream>>>(wav, lo, bd, lw, lb, Bts, out);
    } else {
        fse_main_valu<<<1024, BLOCK, 0, stream>>>(wav, lo, bd, lw, lb, out);
    }
}